// Round 3
// baseline (1315.349 us; speedup 1.0000x reference)
//
#include <hip/hip_runtime.h>
#include <hip/hip_bf16.h>

#define S_N 100000
#define E_N 30000
#define K_N 1000
#define D_K 64
#define F_K 128
#define B_N 16384
#define NNZ_S 1600000
#define NNZ_E 480000
#define NNZ_K 32000
#define NNZ_TOT (NNZ_S + NNZ_E + NNZ_K)

// scan chunking: 2048 elements per block (256 threads x 8)
#define CH_S 49   // ceil(100000/2048)
#define CH_E 15   // ceil(30000/2048)
#define CH_K 1
#define CH_TOT (CH_S + CH_E + CH_K)

// 128-row buckets for the two-stage scatter
#define NB_S 782  // ceil(100000/128)
#define NB_E 235  // ceil(30000/128)
#define NB_K 8    // ceil(1000/128)
#define NB_TOT (NB_S + NB_E + NB_K)

typedef __attribute__((ext_vector_type(8))) short sh8;
typedef __attribute__((ext_vector_type(4))) float f4;

__device__ inline float b2f(ushort u) { return __uint_as_float((unsigned)u << 16); }
__device__ inline ushort f2b(float f) {
    unsigned u = __float_as_uint(f);
    return (ushort)((u + 0x7fffu + ((u >> 16) & 1u)) >> 16);
}

// ---------------------------------------------------------------- CSR build
__global__ void count_kernel(const int* __restrict__ sr, const int* __restrict__ er,
                             const int* __restrict__ kr,
                             int* cnt_s, int* cnt_e, int* cnt_k) {
    int i = blockIdx.x * 256 + threadIdx.x;
    if (i >= NNZ_TOT) return;
    if (i < NNZ_S) atomicAdd(&cnt_s[sr[i]], 1);
    else if (i < NNZ_S + NNZ_E) atomicAdd(&cnt_e[er[i - NNZ_S]], 1);
    else atomicAdd(&cnt_k[kr[i - NNZ_S - NNZ_E]], 1);
}

__device__ inline void seg_map(int b, const int* cnt_s, const int* cnt_e, const int* cnt_k,
                               const int** src, int* len, int* chunk, int* seg) {
    if (b < CH_S)            { *src = cnt_s; *len = S_N; *chunk = b;            *seg = 0; }
    else if (b < CH_S + CH_E){ *src = cnt_e; *len = E_N; *chunk = b - CH_S;     *seg = 1; }
    else                     { *src = cnt_k; *len = K_N; *chunk = 0;            *seg = 2; }
}

__global__ void scan_a(const int* cnt_s, const int* cnt_e, const int* cnt_k, int* partials) {
    const int* src; int len, chunk, seg;
    seg_map(blockIdx.x, cnt_s, cnt_e, cnt_k, &src, &len, &chunk, &seg);
    int base = chunk * 2048 + threadIdx.x * 8;
    int s = 0;
    for (int j = 0; j < 8; j++) { int idx = base + j; if (idx < len) s += src[idx]; }
    __shared__ int red[256];
    red[threadIdx.x] = s; __syncthreads();
    for (int off = 128; off > 0; off >>= 1) {
        if (threadIdx.x < off) red[threadIdx.x] += red[threadIdx.x + off];
        __syncthreads();
    }
    if (threadIdx.x == 0) partials[blockIdx.x] = red[0];
}

__global__ void scan_b(const int* partials, int* chunk_off, int* rp_s, int* rp_e, int* rp_k) {
    if (threadIdx.x == 0 && blockIdx.x == 0) {
        int acc = 0;
        for (int i = 0; i < CH_S; i++) { chunk_off[i] = acc; acc += partials[i]; }
        rp_s[S_N] = acc;
        acc = 0;
        for (int i = CH_S; i < CH_S + CH_E; i++) { chunk_off[i] = acc; acc += partials[i]; }
        rp_e[E_N] = acc;
        chunk_off[CH_S + CH_E] = 0;
        rp_k[K_N] = partials[CH_S + CH_E];
    }
}

__global__ void scan_c(const int* cnt_s, const int* cnt_e, const int* cnt_k,
                       const int* chunk_off,
                       int* rp_s, int* rp_e, int* rp_k) {
    const int* src; int len, chunk, seg;
    seg_map(blockIdx.x, cnt_s, cnt_e, cnt_k, &src, &len, &chunk, &seg);
    int* rp = (seg == 0) ? rp_s : (seg == 1) ? rp_e : rp_k;
    int t = threadIdx.x;
    int base = chunk * 2048 + t * 8;
    int v[8]; int s = 0;
    for (int j = 0; j < 8; j++) { int idx = base + j; v[j] = (idx < len) ? src[idx] : 0; s += v[j]; }
    __shared__ int sd[256];
    sd[t] = s; __syncthreads();
    for (int off = 1; off < 256; off <<= 1) {
        int x = (t >= off) ? sd[t - off] : 0;
        __syncthreads();
        sd[t] += x;
        __syncthreads();
    }
    int pre = sd[t] - s + chunk_off[blockIdx.x];
    for (int j = 0; j < 8; j++) {
        int idx = base + j;
        if (idx < len) { rp[idx] = pre; pre += v[j]; }
    }
}

// ---- two-stage scatter: bucket-bin (adjacent concurrent appends), then place
// stage 1: entry -> bucket window [rp[b*128], rp[(b+1)*128]); packed (r_rel<<25|col, val)
__global__ void stage1_bin(const int* __restrict__ sr, const int* __restrict__ sc,
                           const float* __restrict__ sv,
                           const int* __restrict__ er, const int* __restrict__ ec,
                           const float* __restrict__ ev,
                           const int* __restrict__ kr, const int* __restrict__ kc,
                           const float* __restrict__ kv,
                           const int* __restrict__ rp_s, const int* __restrict__ rp_e,
                           const int* __restrict__ rp_k,
                           int* bcnt, int2* stg_s, int2* stg_e, int2* stg_k) {
    int i = blockIdx.x * 256 + threadIdx.x;
    if (i >= NNZ_TOT) return;
    const int* rows; const int* cols; const float* vals; const int* rp;
    int2* stg; int boff; int ii;
    if (i < NNZ_S) { ii = i; rows = sr; cols = sc; vals = sv; rp = rp_s; stg = stg_s; boff = 0; }
    else if (i < NNZ_S + NNZ_E) { ii = i - NNZ_S; rows = er; cols = ec; vals = ev; rp = rp_e; stg = stg_e; boff = NB_S; }
    else { ii = i - NNZ_S - NNZ_E; rows = kr; cols = kc; vals = kv; rp = rp_k; stg = stg_k; boff = NB_S + NB_E; }
    int r = rows[ii];
    int b = r >> 7;
    int base = rp[b << 7];
    int p = atomicAdd(&bcnt[boff + b], 1);
    int packed = ((r & 127) << 25) | cols[ii];
    stg[base + p] = make_int2(packed, __float_as_int(vals[ii]));
}

// stage 2: block per bucket; LDS per-row cursors; coalesced read, windowed write
__global__ void stage2_place(const int* __restrict__ rp_s, const int2* __restrict__ stg_s,
                             int2* pr_s,
                             const int* __restrict__ rp_e, const int2* __restrict__ stg_e,
                             int2* pr_e,
                             const int* __restrict__ rp_k, const int2* __restrict__ stg_k,
                             int2* pr_k) {
    int b = blockIdx.x;
    const int* rp; const int2* stg; int2* pr; int len;
    if (b < NB_S) { rp = rp_s; stg = stg_s; pr = pr_s; len = S_N; }
    else if (b < NB_S + NB_E) { b -= NB_S; rp = rp_e; stg = stg_e; pr = pr_e; len = E_N; }
    else { b -= NB_S + NB_E; rp = rp_k; stg = stg_k; pr = pr_k; len = K_N; }
    int r0 = b << 7;
    int rows = min(128, len - r0);
    __shared__ int nx[128];
    int t = threadIdx.x;
    if (t < rows) nx[t] = rp[r0 + t];
    __syncthreads();
    int j0 = rp[r0], j1 = rp[r0 + rows];
    for (int j = j0 + t; j < j1; j += 256) {
        int2 e = stg[j];
        int r_rel = ((unsigned)e.x) >> 25;
        int col = e.x & 0x01FFFFFF;
        int p = atomicAdd(&nx[r_rel], 1);
        pr[p] = make_int2(col, e.y);
    }
}

// ------------------------------------------------ f32 -> bf16 convert (embs)
__global__ void convert_bf16(const float* __restrict__ a, const float* __restrict__ b,
                             const float* __restrict__ c,
                             ushort* oa, ushort* ob, ushort* oc) {
    const int NA = S_N * 64, NB = E_N * 64, NC = K_N * 64;
    int i = (blockIdx.x * 256 + threadIdx.x) * 4;
    const float* src; ushort* dst;
    if (i < NA) { src = a; dst = oa; }
    else if (i < NA + NB) { i -= NA; src = b; dst = ob; }
    else if (i < NA + NB + NC) { i -= NA + NB; src = c; dst = oc; }
    else return;
    float4 v = *(const float4*)&src[i];
    ushort4 o;
    o.x = f2b(v.x); o.y = f2b(v.y); o.z = f2b(v.z); o.w = f2b(v.w);
    *(ushort4*)&dst[i] = o;
}

// --------------------------------------------------------- convolution SpMM
// one wave per row, lane = feature d; y[r] = 0.9*x[r] + sum val*x[col]
// bf16 x/y, f32 accumulate, nnz loop unrolled x8 for memory-level parallelism
__global__ void spmm3(const int* __restrict__ rp_s, const int2* __restrict__ pr_s,
                      const ushort* __restrict__ xs, ushort* ys,
                      const int* __restrict__ rp_e, const int2* __restrict__ pr_e,
                      const ushort* __restrict__ xe, ushort* ye,
                      const int* __restrict__ rp_k, const int2* __restrict__ pr_k,
                      const ushort* __restrict__ xk, ushort* yk) {
    int w = (blockIdx.x * 256 + threadIdx.x) >> 6;
    int d = threadIdx.x & 63;
    const int* rp; const int2* pr; const ushort* x; ushort* y; int r;
    if (w < S_N) { rp = rp_s; pr = pr_s; x = xs; y = ys; r = w; }
    else if (w < S_N + E_N) { rp = rp_e; pr = pr_e; x = xe; y = ye; r = w - S_N; }
    else if (w < S_N + E_N + K_N) { rp = rp_k; pr = pr_k; x = xk; y = yk; r = w - S_N - E_N; }
    else return;
    int j0 = rp[r], j1 = rp[r + 1];
    float acc = 0.9f * b2f(x[(long)r * 64 + d]);
    int j = j0;
    for (; j + 8 <= j1; j += 8) {
        int2 p0 = pr[j], p1 = pr[j + 1], p2 = pr[j + 2], p3 = pr[j + 3];
        int2 p4 = pr[j + 4], p5 = pr[j + 5], p6 = pr[j + 6], p7 = pr[j + 7];
        float x0 = b2f(x[(long)p0.x * 64 + d]);
        float x1 = b2f(x[(long)p1.x * 64 + d]);
        float x2 = b2f(x[(long)p2.x * 64 + d]);
        float x3 = b2f(x[(long)p3.x * 64 + d]);
        float x4 = b2f(x[(long)p4.x * 64 + d]);
        float x5 = b2f(x[(long)p5.x * 64 + d]);
        float x6 = b2f(x[(long)p6.x * 64 + d]);
        float x7 = b2f(x[(long)p7.x * 64 + d]);
        acc = fmaf(__int_as_float(p0.y), x0, acc);
        acc = fmaf(__int_as_float(p1.y), x1, acc);
        acc = fmaf(__int_as_float(p2.y), x2, acc);
        acc = fmaf(__int_as_float(p3.y), x3, acc);
        acc = fmaf(__int_as_float(p4.y), x4, acc);
        acc = fmaf(__int_as_float(p5.y), x5, acc);
        acc = fmaf(__int_as_float(p6.y), x6, acc);
        acc = fmaf(__int_as_float(p7.y), x7, acc);
    }
    for (; j < j1; j++) {
        int2 p = pr[j];
        acc = fmaf(__int_as_float(p.y), b2f(x[(long)p.x * 64 + d]), acc);
    }
    y[(long)r * 64 + d] = f2b(acc);
}

// ------------------------------------------------- batch accumulator gathers
// layer-0 init from f32 embeddings
__global__ void gather_init(const int* __restrict__ sid, const int* __restrict__ eid,
                            const float* __restrict__ src_s, const float* __restrict__ src_e,
                            const float* __restrict__ src_k,
                            float* bacc_s, float* bacc_e, float* kacc) {
    int i = blockIdx.x * 256 + threadIdx.x;
    const int BD = B_N * 64;
    if (i < BD) {
        int b = i >> 6, d = i & 63;
        bacc_s[i] = src_s[(long)sid[b] * 64 + d];
    } else if (i < 2 * BD) {
        int ii = i - BD; int b = ii >> 6, d = ii & 63;
        bacc_e[ii] = src_e[(long)eid[b] * 64 + d];
    } else if (i < 2 * BD + K_N * 64) {
        int ii = i - 2 * BD;
        kacc[ii] = src_k[ii];
    }
}

// layers 1..3 accumulate from bf16 conv outputs
__global__ void gather_accb(const int* __restrict__ sid, const int* __restrict__ eid,
                            const ushort* __restrict__ src_s, const ushort* __restrict__ src_e,
                            const ushort* __restrict__ src_k,
                            float* bacc_s, float* bacc_e, float* kacc) {
    int i = blockIdx.x * 256 + threadIdx.x;
    const int BD = B_N * 64;
    if (i < BD) {
        int b = i >> 6, d = i & 63;
        bacc_s[i] += b2f(src_s[(long)sid[b] * 64 + d]);
    } else if (i < 2 * BD) {
        int ii = i - BD; int b = ii >> 6, d = ii & 63;
        bacc_e[ii] += b2f(src_e[(long)eid[b] * 64 + d]);
    } else if (i < 2 * BD + K_N * 64) {
        int ii = i - 2 * BD;
        kacc[ii] += b2f(src_k[ii]);
    }
}

// --------------------------------------------- small dense layers (D=64 -> F=128)
// block: 2 rows x 128 cols; X = 0.25*(bacc + cur3[id]); out = leaky(X@W + b) in bf16
__global__ void dense_mm(const int* __restrict__ sid, const int* __restrict__ eid,
                         const float* __restrict__ bacc_s, const ushort* __restrict__ cur3_s,
                         const float* __restrict__ bacc_e, const ushort* __restrict__ cur3_e,
                         const float* __restrict__ W_stu, const float* __restrict__ b_stu,
                         const float* __restrict__ W_exer, const float* __restrict__ b_exer,
                         __hip_bfloat16* st_b, __hip_bfloat16* df_b) {
    int which = blockIdx.y;
    const int* id = which ? eid : sid;
    const float* bacc = which ? bacc_e : bacc_s;
    const ushort* cur3 = which ? cur3_e : cur3_s;
    const float* W = which ? W_exer : W_stu;
    const float* bias = which ? b_exer : b_stu;
    __hip_bfloat16* out = which ? df_b : st_b;
    int r0 = blockIdx.x * 2;
    int t = threadIdx.x;
    __shared__ float X[2][64];
    if (t < 128) {
        int lr = t >> 6, d = t & 63; int b = r0 + lr;
        X[lr][d] = 0.25f * (bacc[(long)b * 64 + d] + b2f(cur3[(long)id[b] * 64 + d]));
    }
    __syncthreads();
    int lr = t >> 7, f = t & 127;
    float acc = bias[f];
    for (int d = 0; d < 64; d++) acc += X[lr][d] * W[d * 128 + f];
    acc = acc > 0.f ? acc : 0.1f * acc;
    out[(long)(r0 + lr) * 128 + f] = __float2bfloat16(acc);
}

// knowledge: rows padded to 1024; writes f32 to d_out and bf16 (zero-padded) to ws
__global__ void know_mm(const float* __restrict__ kacc, const ushort* __restrict__ cur3_k,
                        const float* __restrict__ W, const float* __restrict__ bias,
                        float* out_f32, __hip_bfloat16* kn_b) {
    int r0 = blockIdx.x * 2;
    int t = threadIdx.x;
    __shared__ float X[2][64];
    if (t < 128) {
        int lr = t >> 6, d = t & 63; int r = r0 + lr;
        X[lr][d] = (r < K_N) ? 0.25f * (kacc[r * 64 + d] + b2f(cur3_k[r * 64 + d])) : 0.f;
    }
    __syncthreads();
    int lr = t >> 7, f = t & 127; int r = r0 + lr;
    float acc = bias[f];
    for (int d = 0; d < 64; d++) acc += X[lr][d] * W[d * 128 + f];
    acc = acc > 0.f ? acc : 0.1f * acc;
    if (r < K_N) {
        out_f32[(long)r * 128 + f] = acc;
        kn_b[(long)r * 128 + f] = __float2bfloat16(acc);
    } else {
        kn_b[(long)r * 128 + f] = __float2bfloat16(0.f);
    }
}

// disc = sigmoid(0.25*(bacc_e+cur3_e[eid]) . W_disc + b_disc), one wave per row
__global__ void disc_kernel(const int* __restrict__ eid,
                            const float* __restrict__ bacc_e, const ushort* __restrict__ cur3_e,
                            const float* __restrict__ W_disc, const float* __restrict__ b_disc,
                            float* out) {
    int w = (blockIdx.x * 256 + threadIdx.x) >> 6;
    int d = threadIdx.x & 63;
    if (w >= B_N) return;
    float x = 0.25f * (bacc_e[(long)w * 64 + d] + b2f(cur3_e[(long)eid[w] * 64 + d])) * W_disc[d];
    for (int off = 32; off > 0; off >>= 1) x += __shfl_down(x, off, 64);
    if (d == 0) {
        float z = x + b_disc[0];
        out[w] = 1.f / (1.f + expf(-z));
    }
}

__global__ void impact_kernel(const int* __restrict__ eid, const float* __restrict__ imp,
                              float* out) {
    int i = blockIdx.x * 256 + threadIdx.x;
    if (i >= B_N * 64) return;
    int b = i >> 6, d = i & 63;
    out[i] = imp[(long)eid[b] * 64 + d];
}

// --------------------------------------------- big GEMM: [B,128] @ [128,1024p]^T
// wave computes 32x32 (2x2 tiles of mfma_f32_16x16x32_bf16), block = 4 waves = 64x64
__global__ void big_mm(const __hip_bfloat16* __restrict__ st, const __hip_bfloat16* __restrict__ df,
                       const __hip_bfloat16* __restrict__ kn,
                       float* __restrict__ out0, float* __restrict__ out1) {
    const ushort* X = (const ushort*)(blockIdx.z ? df : st);
    const ushort* Kn = (const ushort*)kn;
    float* out = blockIdx.z ? out1 : out0;
    int wv = threadIdx.x >> 6;
    int lane = threadIdx.x & 63;
    int m_blk = blockIdx.y * 64 + (wv >> 1) * 32;
    int n_blk = blockIdx.x * 64 + (wv & 1) * 32;
    int q = lane >> 4, l16 = lane & 15;
    f4 acc00 = {0.f, 0.f, 0.f, 0.f}, acc01 = acc00, acc10 = acc00, acc11 = acc00;
    for (int s = 0; s < 4; s++) {
        int kofs = s * 32 + q * 8;
        sh8 a0 = *(const sh8*)&X[(long)(m_blk + l16) * 128 + kofs];
        sh8 a1 = *(const sh8*)&X[(long)(m_blk + 16 + l16) * 128 + kofs];
        sh8 b0 = *(const sh8*)&Kn[(long)(n_blk + l16) * 128 + kofs];
        sh8 b1 = *(const sh8*)&Kn[(long)(n_blk + 16 + l16) * 128 + kofs];
        acc00 = __builtin_amdgcn_mfma_f32_16x16x32_bf16(a0, b0, acc00, 0, 0, 0);
        acc01 = __builtin_amdgcn_mfma_f32_16x16x32_bf16(a0, b1, acc01, 0, 0, 0);
        acc10 = __builtin_amdgcn_mfma_f32_16x16x32_bf16(a1, b0, acc10, 0, 0, 0);
        acc11 = __builtin_amdgcn_mfma_f32_16x16x32_bf16(a1, b1, acc11, 0, 0, 0);
    }
    // C/D layout: col = lane&15, row = (lane>>4)*4 + reg
    for (int r = 0; r < 4; r++) {
        int row0 = m_blk + q * 4 + r;
        int row1 = m_blk + 16 + q * 4 + r;
        int col0 = n_blk + l16;
        int col1 = n_blk + 16 + l16;
        if (col0 < K_N) {
            out[(long)row0 * K_N + col0] = acc00[r];
            out[(long)row1 * K_N + col0] = acc10[r];
        }
        if (col1 < K_N) {
            out[(long)row0 * K_N + col1] = acc01[r];
            out[(long)row1 * K_N + col1] = acc11[r];
        }
    }
}

// ---------------------------------------------------------------------------
extern "C" void kernel_launch(void* const* d_in, const int* in_sizes, int n_in,
                              void* d_out, int out_size, void* d_ws, size_t ws_size,
                              hipStream_t stream) {
    const int* sid = (const int*)d_in[0];
    const int* eid = (const int*)d_in[1];
    // d_in[2] q_mask unused
    const float* stu_emb = (const float*)d_in[3];
    const float* exer_emb = (const float*)d_in[4];
    const float* know_emb = (const float*)d_in[5];
    const float* impact_emb = (const float*)d_in[6];
    const int* s_rows = (const int*)d_in[7];
    const int* s_cols = (const int*)d_in[8];
    const float* s_vals = (const float*)d_in[9];
    const int* e_rows = (const int*)d_in[10];
    const int* e_cols = (const int*)d_in[11];
    const float* e_vals = (const float*)d_in[12];
    const int* k_rows = (const int*)d_in[13];
    const int* k_cols = (const int*)d_in[14];
    const float* k_vals = (const float*)d_in[15];
    const float* W_stu = (const float*)d_in[16];
    const float* b_stu = (const float*)d_in[17];
    const float* W_exer = (const float*)d_in[18];
    const float* b_exer = (const float*)d_in[19];
    const float* W_know = (const float*)d_in[20];
    const float* b_know = (const float*)d_in[21];
    const float* W_disc = (const float*)d_in[22];
    const float* b_disc = (const float*)d_in[23];

    float* out = (float*)d_out;
    float* out_st = out;                       // [B,1000]
    float* out_df = out + 16384000;            // [B,1000]
    float* out_disc = out + 32768000;          // [B,1]
    float* out_kn = out + 32784384;            // [1000,128]
    float* out_imp = out + 32912384;           // [B,64]

    char* p = (char*)d_ws;
    auto alloc = [&](size_t bytes) -> char* {
        char* r = p;
        p += (bytes + 255) & ~(size_t)255;
        return r;
    };
    ushort* xb_s = (ushort*)alloc((size_t)S_N * 64 * 2);   // bf16 embeddings
    ushort* xb_e = (ushort*)alloc((size_t)E_N * 64 * 2);
    ushort* xb_k = (ushort*)alloc((size_t)K_N * 64 * 2);
    ushort* bufA_s = (ushort*)alloc((size_t)S_N * 64 * 2);
    ushort* bufB_s = (ushort*)alloc((size_t)S_N * 64 * 2);
    ushort* bufA_e = (ushort*)alloc((size_t)E_N * 64 * 2);
    ushort* bufB_e = (ushort*)alloc((size_t)E_N * 64 * 2);
    ushort* bufA_k = (ushort*)alloc((size_t)K_N * 64 * 2);
    ushort* bufB_k = (ushort*)alloc((size_t)K_N * 64 * 2);
    float* bacc_s = (float*)alloc((size_t)B_N * 64 * 4);
    float* bacc_e = (float*)alloc((size_t)B_N * 64 * 4);
    float* kacc = (float*)alloc((size_t)K_N * 64 * 4);
    __hip_bfloat16* st_b = (__hip_bfloat16*)alloc((size_t)B_N * 128 * 2);
    __hip_bfloat16* df_b = (__hip_bfloat16*)alloc((size_t)B_N * 128 * 2);
    __hip_bfloat16* kn_b = (__hip_bfloat16*)alloc((size_t)1024 * 128 * 2);
    // counters: cnt_s/cnt_e/cnt_k + bucket counters, contiguous for one memset
    int* cnt_s = (int*)alloc((size_t)(S_N + E_N + K_N + NB_TOT) * 4);
    int* cnt_e = cnt_s + S_N;
    int* cnt_k = cnt_e + E_N;
    int* bcnt = cnt_k + K_N;
    int* rp_s = (int*)alloc((size_t)(S_N + 1) * 4);
    int* rp_e = (int*)alloc((size_t)(E_N + 1) * 4);
    int* rp_k = (int*)alloc((size_t)(K_N + 1) * 4);
    int2* stg_s = (int2*)alloc((size_t)NNZ_S * 8);
    int2* stg_e = (int2*)alloc((size_t)NNZ_E * 8);
    int2* stg_k = (int2*)alloc((size_t)NNZ_K * 8);
    int2* pr_s = (int2*)alloc((size_t)NNZ_S * 8);
    int2* pr_e = (int2*)alloc((size_t)NNZ_E * 8);
    int2* pr_k = (int2*)alloc((size_t)NNZ_K * 8);
    int* partials = (int*)alloc(CH_TOT * 4);
    int* chunk_off = (int*)alloc(CH_TOT * 4);

    // ---- CSR build
    hipMemsetAsync(cnt_s, 0, (size_t)(S_N + E_N + K_N + NB_TOT) * 4, stream);
    count_kernel<<<NNZ_TOT / 256, 256, 0, stream>>>(s_rows, e_rows, k_rows, cnt_s, cnt_e, cnt_k);
    scan_a<<<CH_TOT, 256, 0, stream>>>(cnt_s, cnt_e, cnt_k, partials);
    scan_b<<<1, 64, 0, stream>>>(partials, chunk_off, rp_s, rp_e, rp_k);
    scan_c<<<CH_TOT, 256, 0, stream>>>(cnt_s, cnt_e, cnt_k, chunk_off, rp_s, rp_e, rp_k);
    stage1_bin<<<NNZ_TOT / 256, 256, 0, stream>>>(
        s_rows, s_cols, s_vals, e_rows, e_cols, e_vals, k_rows, k_cols, k_vals,
        rp_s, rp_e, rp_k, bcnt, stg_s, stg_e, stg_k);
    stage2_place<<<NB_TOT, 256, 0, stream>>>(rp_s, stg_s, pr_s,
                                             rp_e, stg_e, pr_e,
                                             rp_k, stg_k, pr_k);

    // ---- bf16 convert of embeddings (spmm inputs)
    const int conv_blocks = ((S_N + E_N + K_N) * 64 / 4 + 255) / 256;
    convert_bf16<<<conv_blocks, 256, 0, stream>>>(stu_emb, exer_emb, know_emb, xb_s, xb_e, xb_k);

    // ---- convolution: G1(emb f32), L1, G2(cur1), L2, G3(cur2), L3
    const int gather_blocks = (2 * B_N * 64 + K_N * 64) / 256;
    const int spmm_blocks = (S_N + E_N + K_N + 3) / 4;
    gather_init<<<gather_blocks, 256, 0, stream>>>(sid, eid, stu_emb, exer_emb, know_emb,
                                                   bacc_s, bacc_e, kacc);
    spmm3<<<spmm_blocks, 256, 0, stream>>>(rp_s, pr_s, xb_s, bufA_s,
                                           rp_e, pr_e, xb_e, bufA_e,
                                           rp_k, pr_k, xb_k, bufA_k);
    gather_accb<<<gather_blocks, 256, 0, stream>>>(sid, eid, bufA_s, bufA_e, bufA_k,
                                                   bacc_s, bacc_e, kacc);
    spmm3<<<spmm_blocks, 256, 0, stream>>>(rp_s, pr_s, bufA_s, bufB_s,
                                           rp_e, pr_e, bufA_e, bufB_e,
                                           rp_k, pr_k, bufA_k, bufB_k);
    gather_accb<<<gather_blocks, 256, 0, stream>>>(sid, eid, bufB_s, bufB_e, bufB_k,
                                                   bacc_s, bacc_e, kacc);
    spmm3<<<spmm_blocks, 256, 0, stream>>>(rp_s, pr_s, bufB_s, bufA_s,
                                           rp_e, pr_e, bufB_e, bufA_e,
                                           rp_k, pr_k, bufB_k, bufA_k);
    // cur3 now in bufA_* (bf16); dense stage folds the last gather and the /4 scale

    // ---- dense stage
    dense_mm<<<dim3(B_N / 2, 2), 256, 0, stream>>>(sid, eid, bacc_s, bufA_s, bacc_e, bufA_e,
                                                   W_stu, b_stu, W_exer, b_exer, st_b, df_b);
    know_mm<<<512, 256, 0, stream>>>(kacc, bufA_k, W_know, b_know, out_kn, kn_b);
    disc_kernel<<<B_N / 4, 256, 0, stream>>>(eid, bacc_e, bufA_e, W_disc, b_disc, out_disc);
    impact_kernel<<<B_N * 64 / 256, 256, 0, stream>>>(eid, impact_emb, out_imp);

    // ---- big GEMMs: [B,128] @ kn^T -> [B,1000], both in one kernel (z = 0/1)
    big_mm<<<dim3(16, B_N / 64, 2), 256, 0, stream>>>(st_b, df_b, kn_b, out_st, out_df);
}

// Round 4
// 808.723 us; speedup vs baseline: 1.6265x; 1.6265x over previous
//
#include <hip/hip_runtime.h>
#include <hip/hip_bf16.h>

#define S_N 100000
#define E_N 30000
#define K_N 1000
#define D_K 64
#define F_K 128
#define B_N 16384
#define NNZ_S 1600000
#define NNZ_E 480000
#define NNZ_K 32000
#define NNZ_TOT (NNZ_S + NNZ_E + NNZ_K)

// scan chunking: 2048 elements per block (256 threads x 8)
#define CH_S 49   // ceil(100000/2048)
#define CH_E 15   // ceil(30000/2048)
#define CH_K 1
#define CH_TOT (CH_S + CH_E + CH_K)

// 128-row buckets for the two-stage scatter
#define NB_S 782  // ceil(100000/128)
#define NB_E 235  // ceil(30000/128)
#define NB_K 8    // ceil(1000/128)
#define NB_TOT (NB_S + NB_E + NB_K)

// stage1 block-local binning: 4096 entries per block
#define CHUNK 4096
#define SB_S 391  // ceil(1600000/4096)
#define SB_E 118  // ceil(480000/4096)
#define SB_K 8    // ceil(32000/4096)
#define SB_TOT (SB_S + SB_E + SB_K)

typedef __attribute__((ext_vector_type(8))) short sh8;
typedef __attribute__((ext_vector_type(4))) float f4;

__device__ inline float b2f(ushort u) { return __uint_as_float((unsigned)u << 16); }
__device__ inline ushort f2b(float f) {
    unsigned u = __float_as_uint(f);
    return (ushort)((u + 0x7fffu + ((u >> 16) & 1u)) >> 16);
}

// ---------------------------------------------------------------- CSR build
__global__ void count_kernel(const int* __restrict__ sr, const int* __restrict__ er,
                             const int* __restrict__ kr,
                             int* cnt_s, int* cnt_e, int* cnt_k) {
    int i = blockIdx.x * 256 + threadIdx.x;
    if (i >= NNZ_TOT) return;
    if (i < NNZ_S) atomicAdd(&cnt_s[sr[i]], 1);
    else if (i < NNZ_S + NNZ_E) atomicAdd(&cnt_e[er[i - NNZ_S]], 1);
    else atomicAdd(&cnt_k[kr[i - NNZ_S - NNZ_E]], 1);
}

__device__ inline void seg_map(int b, const int* cnt_s, const int* cnt_e, const int* cnt_k,
                               const int** src, int* len, int* chunk, int* seg) {
    if (b < CH_S)            { *src = cnt_s; *len = S_N; *chunk = b;            *seg = 0; }
    else if (b < CH_S + CH_E){ *src = cnt_e; *len = E_N; *chunk = b - CH_S;     *seg = 1; }
    else                     { *src = cnt_k; *len = K_N; *chunk = 0;            *seg = 2; }
}

__global__ void scan_a(const int* cnt_s, const int* cnt_e, const int* cnt_k, int* partials) {
    const int* src; int len, chunk, seg;
    seg_map(blockIdx.x, cnt_s, cnt_e, cnt_k, &src, &len, &chunk, &seg);
    int base = chunk * 2048 + threadIdx.x * 8;
    int s = 0;
    for (int j = 0; j < 8; j++) { int idx = base + j; if (idx < len) s += src[idx]; }
    __shared__ int red[256];
    red[threadIdx.x] = s; __syncthreads();
    for (int off = 128; off > 0; off >>= 1) {
        if (threadIdx.x < off) red[threadIdx.x] += red[threadIdx.x + off];
        __syncthreads();
    }
    if (threadIdx.x == 0) partials[blockIdx.x] = red[0];
}

__global__ void scan_b(const int* partials, int* chunk_off, int* rp_s, int* rp_e, int* rp_k) {
    if (threadIdx.x == 0 && blockIdx.x == 0) {
        int acc = 0;
        for (int i = 0; i < CH_S; i++) { chunk_off[i] = acc; acc += partials[i]; }
        rp_s[S_N] = acc;
        acc = 0;
        for (int i = CH_S; i < CH_S + CH_E; i++) { chunk_off[i] = acc; acc += partials[i]; }
        rp_e[E_N] = acc;
        chunk_off[CH_S + CH_E] = 0;
        rp_k[K_N] = partials[CH_S + CH_E];
    }
}

__global__ void scan_c(const int* cnt_s, const int* cnt_e, const int* cnt_k,
                       const int* chunk_off,
                       int* rp_s, int* rp_e, int* rp_k) {
    const int* src; int len, chunk, seg;
    seg_map(blockIdx.x, cnt_s, cnt_e, cnt_k, &src, &len, &chunk, &seg);
    int* rp = (seg == 0) ? rp_s : (seg == 1) ? rp_e : rp_k;
    int t = threadIdx.x;
    int base = chunk * 2048 + t * 8;
    int v[8]; int s = 0;
    for (int j = 0; j < 8; j++) { int idx = base + j; v[j] = (idx < len) ? src[idx] : 0; s += v[j]; }
    __shared__ int sd[256];
    sd[t] = s; __syncthreads();
    for (int off = 1; off < 256; off <<= 1) {
        int x = (t >= off) ? sd[t - off] : 0;
        __syncthreads();
        sd[t] += x;
        __syncthreads();
    }
    int pre = sd[t] - s + chunk_off[blockIdx.x];
    for (int j = 0; j < 8; j++) {
        int idx = base + j;
        if (idx < len) { rp[idx] = pre; pre += v[j]; }
    }
}

// ---- stage 1 v2: block-local LDS binning.
// Each block owns a 4096-entry chunk: LDS histogram -> one global atomic per
// non-empty bucket (reserves a contiguous run in the bucket's CSR window) ->
// re-read & place via LDS cursors. Global atomics: ~300K @ ~390/address
// (vs R3's 2.1M @ ~2000/address); writes are private contiguous runs.
__global__ void stage1_bin(const int* __restrict__ sr, const int* __restrict__ sc,
                           const float* __restrict__ sv,
                           const int* __restrict__ er, const int* __restrict__ ec,
                           const float* __restrict__ ev,
                           const int* __restrict__ kr, const int* __restrict__ kc,
                           const float* __restrict__ kv,
                           const int* __restrict__ rp_s, const int* __restrict__ rp_e,
                           const int* __restrict__ rp_k,
                           int* bcnt, int2* stg_s, int2* stg_e, int2* stg_k) {
    int blk = blockIdx.x;
    const int* rows; const int* cols; const float* vals; const int* rp;
    int2* stg; int boff, nnz, nb, lblk;
    if (blk < SB_S) {
        lblk = blk; rows = sr; cols = sc; vals = sv; rp = rp_s; stg = stg_s;
        boff = 0; nnz = NNZ_S; nb = NB_S;
    } else if (blk < SB_S + SB_E) {
        lblk = blk - SB_S; rows = er; cols = ec; vals = ev; rp = rp_e; stg = stg_e;
        boff = NB_S; nnz = NNZ_E; nb = NB_E;
    } else {
        lblk = blk - SB_S - SB_E; rows = kr; cols = kc; vals = kv; rp = rp_k; stg = stg_k;
        boff = NB_S + NB_E; nnz = NNZ_K; nb = NB_K;
    }
    __shared__ int hist[NB_S];
    __shared__ int wbase[NB_S];
    int t = threadIdx.x;
    for (int i = t; i < nb; i += 256) hist[i] = 0;
    __syncthreads();
    int start = lblk * CHUNK, end = min(start + CHUNK, nnz);
    for (int i = start + t; i < end; i += 256) atomicAdd(&hist[rows[i] >> 7], 1);
    __syncthreads();
    for (int i = t; i < nb; i += 256) {
        int h = hist[i];
        int b0 = h ? atomicAdd(&bcnt[boff + i], h) : 0;
        wbase[i] = rp[i << 7] + b0;
        hist[i] = 0;
    }
    __syncthreads();
    for (int i = start + t; i < end; i += 256) {
        int r = rows[i]; int b = r >> 7;
        int p = wbase[b] + atomicAdd(&hist[b], 1);
        stg[p] = make_int2(((r & 127) << 25) | cols[i], __float_as_int(vals[i]));
    }
}

// stage 2: block per bucket; LDS per-row cursors; coalesced read, windowed write
__global__ void stage2_place(const int* __restrict__ rp_s, const int2* __restrict__ stg_s,
                             int2* pr_s,
                             const int* __restrict__ rp_e, const int2* __restrict__ stg_e,
                             int2* pr_e,
                             const int* __restrict__ rp_k, const int2* __restrict__ stg_k,
                             int2* pr_k) {
    int b = blockIdx.x;
    const int* rp; const int2* stg; int2* pr; int len;
    if (b < NB_S) { rp = rp_s; stg = stg_s; pr = pr_s; len = S_N; }
    else if (b < NB_S + NB_E) { b -= NB_S; rp = rp_e; stg = stg_e; pr = pr_e; len = E_N; }
    else { b -= NB_S + NB_E; rp = rp_k; stg = stg_k; pr = pr_k; len = K_N; }
    int r0 = b << 7;
    int rows = min(128, len - r0);
    __shared__ int nx[128];
    int t = threadIdx.x;
    if (t < rows) nx[t] = rp[r0 + t];
    __syncthreads();
    int j0 = rp[r0], j1 = rp[r0 + rows];
    for (int j = j0 + t; j < j1; j += 256) {
        int2 e = stg[j];
        int r_rel = ((unsigned)e.x) >> 25;
        int col = e.x & 0x01FFFFFF;
        int p = atomicAdd(&nx[r_rel], 1);
        pr[p] = make_int2(col, e.y);
    }
}

// ------------------------------------------------ f32 -> bf16 convert (embs)
__global__ void convert_bf16(const float* __restrict__ a, const float* __restrict__ b,
                             const float* __restrict__ c,
                             ushort* oa, ushort* ob, ushort* oc) {
    const int NA = S_N * 64, NB = E_N * 64, NC = K_N * 64;
    int i = (blockIdx.x * 256 + threadIdx.x) * 4;
    const float* src; ushort* dst;
    if (i < NA) { src = a; dst = oa; }
    else if (i < NA + NB) { i -= NA; src = b; dst = ob; }
    else if (i < NA + NB + NC) { i -= NA + NB; src = c; dst = oc; }
    else return;
    float4 v = *(const float4*)&src[i];
    ushort4 o;
    o.x = f2b(v.x); o.y = f2b(v.y); o.z = f2b(v.z); o.w = f2b(v.w);
    *(ushort4*)&dst[i] = o;
}

// --------------------------------------------------------- convolution SpMM
// one wave per row, lane = feature d; y[r] = 0.9*x[r] + sum val*x[col]
// bf16 x/y, f32 accumulate, nnz loop unrolled x8 for memory-level parallelism
__global__ void spmm3(const int* __restrict__ rp_s, const int2* __restrict__ pr_s,
                      const ushort* __restrict__ xs, ushort* ys,
                      const int* __restrict__ rp_e, const int2* __restrict__ pr_e,
                      const ushort* __restrict__ xe, ushort* ye,
                      const int* __restrict__ rp_k, const int2* __restrict__ pr_k,
                      const ushort* __restrict__ xk, ushort* yk) {
    int w = (blockIdx.x * 256 + threadIdx.x) >> 6;
    int d = threadIdx.x & 63;
    const int* rp; const int2* pr; const ushort* x; ushort* y; int r;
    if (w < S_N) { rp = rp_s; pr = pr_s; x = xs; y = ys; r = w; }
    else if (w < S_N + E_N) { rp = rp_e; pr = pr_e; x = xe; y = ye; r = w - S_N; }
    else if (w < S_N + E_N + K_N) { rp = rp_k; pr = pr_k; x = xk; y = yk; r = w - S_N - E_N; }
    else return;
    int j0 = rp[r], j1 = rp[r + 1];
    float acc = 0.9f * b2f(x[(long)r * 64 + d]);
    int j = j0;
    for (; j + 8 <= j1; j += 8) {
        int2 p0 = pr[j], p1 = pr[j + 1], p2 = pr[j + 2], p3 = pr[j + 3];
        int2 p4 = pr[j + 4], p5 = pr[j + 5], p6 = pr[j + 6], p7 = pr[j + 7];
        float x0 = b2f(x[(long)p0.x * 64 + d]);
        float x1 = b2f(x[(long)p1.x * 64 + d]);
        float x2 = b2f(x[(long)p2.x * 64 + d]);
        float x3 = b2f(x[(long)p3.x * 64 + d]);
        float x4 = b2f(x[(long)p4.x * 64 + d]);
        float x5 = b2f(x[(long)p5.x * 64 + d]);
        float x6 = b2f(x[(long)p6.x * 64 + d]);
        float x7 = b2f(x[(long)p7.x * 64 + d]);
        acc = fmaf(__int_as_float(p0.y), x0, acc);
        acc = fmaf(__int_as_float(p1.y), x1, acc);
        acc = fmaf(__int_as_float(p2.y), x2, acc);
        acc = fmaf(__int_as_float(p3.y), x3, acc);
        acc = fmaf(__int_as_float(p4.y), x4, acc);
        acc = fmaf(__int_as_float(p5.y), x5, acc);
        acc = fmaf(__int_as_float(p6.y), x6, acc);
        acc = fmaf(__int_as_float(p7.y), x7, acc);
    }
    for (; j < j1; j++) {
        int2 p = pr[j];
        acc = fmaf(__int_as_float(p.y), b2f(x[(long)p.x * 64 + d]), acc);
    }
    y[(long)r * 64 + d] = f2b(acc);
}

// ------------------------------------------------- batch accumulator gathers
// layer-0 init from f32 embeddings
__global__ void gather_init(const int* __restrict__ sid, const int* __restrict__ eid,
                            const float* __restrict__ src_s, const float* __restrict__ src_e,
                            const float* __restrict__ src_k,
                            float* bacc_s, float* bacc_e, float* kacc) {
    int i = blockIdx.x * 256 + threadIdx.x;
    const int BD = B_N * 64;
    if (i < BD) {
        int b = i >> 6, d = i & 63;
        bacc_s[i] = src_s[(long)sid[b] * 64 + d];
    } else if (i < 2 * BD) {
        int ii = i - BD; int b = ii >> 6, d = ii & 63;
        bacc_e[ii] = src_e[(long)eid[b] * 64 + d];
    } else if (i < 2 * BD + K_N * 64) {
        int ii = i - 2 * BD;
        kacc[ii] = src_k[ii];
    }
}

// layers 1..3 accumulate from bf16 conv outputs
__global__ void gather_accb(const int* __restrict__ sid, const int* __restrict__ eid,
                            const ushort* __restrict__ src_s, const ushort* __restrict__ src_e,
                            const ushort* __restrict__ src_k,
                            float* bacc_s, float* bacc_e, float* kacc) {
    int i = blockIdx.x * 256 + threadIdx.x;
    const int BD = B_N * 64;
    if (i < BD) {
        int b = i >> 6, d = i & 63;
        bacc_s[i] += b2f(src_s[(long)sid[b] * 64 + d]);
    } else if (i < 2 * BD) {
        int ii = i - BD; int b = ii >> 6, d = ii & 63;
        bacc_e[ii] += b2f(src_e[(long)eid[b] * 64 + d]);
    } else if (i < 2 * BD + K_N * 64) {
        int ii = i - 2 * BD;
        kacc[ii] += b2f(src_k[ii]);
    }
}

// --------------------------------------------- small dense layers (D=64 -> F=128)
// block: 2 rows x 128 cols; X = 0.25*(bacc + cur3[id]); out = leaky(X@W + b) in bf16
__global__ void dense_mm(const int* __restrict__ sid, const int* __restrict__ eid,
                         const float* __restrict__ bacc_s, const ushort* __restrict__ cur3_s,
                         const float* __restrict__ bacc_e, const ushort* __restrict__ cur3_e,
                         const float* __restrict__ W_stu, const float* __restrict__ b_stu,
                         const float* __restrict__ W_exer, const float* __restrict__ b_exer,
                         __hip_bfloat16* st_b, __hip_bfloat16* df_b) {
    int which = blockIdx.y;
    const int* id = which ? eid : sid;
    const float* bacc = which ? bacc_e : bacc_s;
    const ushort* cur3 = which ? cur3_e : cur3_s;
    const float* W = which ? W_exer : W_stu;
    const float* bias = which ? b_exer : b_stu;
    __hip_bfloat16* out = which ? df_b : st_b;
    int r0 = blockIdx.x * 2;
    int t = threadIdx.x;
    __shared__ float X[2][64];
    if (t < 128) {
        int lr = t >> 6, d = t & 63; int b = r0 + lr;
        X[lr][d] = 0.25f * (bacc[(long)b * 64 + d] + b2f(cur3[(long)id[b] * 64 + d]));
    }
    __syncthreads();
    int lr = t >> 7, f = t & 127;
    float acc = bias[f];
    for (int d = 0; d < 64; d++) acc += X[lr][d] * W[d * 128 + f];
    acc = acc > 0.f ? acc : 0.1f * acc;
    out[(long)(r0 + lr) * 128 + f] = __float2bfloat16(acc);
}

// knowledge: rows padded to 1024; writes f32 to d_out and bf16 (zero-padded) to ws
__global__ void know_mm(const float* __restrict__ kacc, const ushort* __restrict__ cur3_k,
                        const float* __restrict__ W, const float* __restrict__ bias,
                        float* out_f32, __hip_bfloat16* kn_b) {
    int r0 = blockIdx.x * 2;
    int t = threadIdx.x;
    __shared__ float X[2][64];
    if (t < 128) {
        int lr = t >> 6, d = t & 63; int r = r0 + lr;
        X[lr][d] = (r < K_N) ? 0.25f * (kacc[r * 64 + d] + b2f(cur3_k[r * 64 + d])) : 0.f;
    }
    __syncthreads();
    int lr = t >> 7, f = t & 127; int r = r0 + lr;
    float acc = bias[f];
    for (int d = 0; d < 64; d++) acc += X[lr][d] * W[d * 128 + f];
    acc = acc > 0.f ? acc : 0.1f * acc;
    if (r < K_N) {
        out_f32[(long)r * 128 + f] = acc;
        kn_b[(long)r * 128 + f] = __float2bfloat16(acc);
    } else {
        kn_b[(long)r * 128 + f] = __float2bfloat16(0.f);
    }
}

// disc = sigmoid(0.25*(bacc_e+cur3_e[eid]) . W_disc + b_disc), one wave per row
__global__ void disc_kernel(const int* __restrict__ eid,
                            const float* __restrict__ bacc_e, const ushort* __restrict__ cur3_e,
                            const float* __restrict__ W_disc, const float* __restrict__ b_disc,
                            float* out) {
    int w = (blockIdx.x * 256 + threadIdx.x) >> 6;
    int d = threadIdx.x & 63;
    if (w >= B_N) return;
    float x = 0.25f * (bacc_e[(long)w * 64 + d] + b2f(cur3_e[(long)eid[w] * 64 + d])) * W_disc[d];
    for (int off = 32; off > 0; off >>= 1) x += __shfl_down(x, off, 64);
    if (d == 0) {
        float z = x + b_disc[0];
        out[w] = 1.f / (1.f + expf(-z));
    }
}

__global__ void impact_kernel(const int* __restrict__ eid, const float* __restrict__ imp,
                              float* out) {
    int i = blockIdx.x * 256 + threadIdx.x;
    if (i >= B_N * 64) return;
    int b = i >> 6, d = i & 63;
    out[i] = imp[(long)eid[b] * 64 + d];
}

// --------------------------------------------- big GEMM: [B,128] @ [128,1024p]^T
// wave computes 32x32 (2x2 tiles of mfma_f32_16x16x32_bf16), block = 4 waves = 64x64
__global__ void big_mm(const __hip_bfloat16* __restrict__ st, const __hip_bfloat16* __restrict__ df,
                       const __hip_bfloat16* __restrict__ kn,
                       float* __restrict__ out0, float* __restrict__ out1) {
    const ushort* X = (const ushort*)(blockIdx.z ? df : st);
    const ushort* Kn = (const ushort*)kn;
    float* out = blockIdx.z ? out1 : out0;
    int wv = threadIdx.x >> 6;
    int lane = threadIdx.x & 63;
    int m_blk = blockIdx.y * 64 + (wv >> 1) * 32;
    int n_blk = blockIdx.x * 64 + (wv & 1) * 32;
    int q = lane >> 4, l16 = lane & 15;
    f4 acc00 = {0.f, 0.f, 0.f, 0.f}, acc01 = acc00, acc10 = acc00, acc11 = acc00;
    for (int s = 0; s < 4; s++) {
        int kofs = s * 32 + q * 8;
        sh8 a0 = *(const sh8*)&X[(long)(m_blk + l16) * 128 + kofs];
        sh8 a1 = *(const sh8*)&X[(long)(m_blk + 16 + l16) * 128 + kofs];
        sh8 b0 = *(const sh8*)&Kn[(long)(n_blk + l16) * 128 + kofs];
        sh8 b1 = *(const sh8*)&Kn[(long)(n_blk + 16 + l16) * 128 + kofs];
        acc00 = __builtin_amdgcn_mfma_f32_16x16x32_bf16(a0, b0, acc00, 0, 0, 0);
        acc01 = __builtin_amdgcn_mfma_f32_16x16x32_bf16(a0, b1, acc01, 0, 0, 0);
        acc10 = __builtin_amdgcn_mfma_f32_16x16x32_bf16(a1, b0, acc10, 0, 0, 0);
        acc11 = __builtin_amdgcn_mfma_f32_16x16x32_bf16(a1, b1, acc11, 0, 0, 0);
    }
    // C/D layout: col = lane&15, row = (lane>>4)*4 + reg
    for (int r = 0; r < 4; r++) {
        int row0 = m_blk + q * 4 + r;
        int row1 = m_blk + 16 + q * 4 + r;
        int col0 = n_blk + l16;
        int col1 = n_blk + 16 + l16;
        if (col0 < K_N) {
            out[(long)row0 * K_N + col0] = acc00[r];
            out[(long)row1 * K_N + col0] = acc10[r];
        }
        if (col1 < K_N) {
            out[(long)row0 * K_N + col1] = acc01[r];
            out[(long)row1 * K_N + col1] = acc11[r];
        }
    }
}

// ---------------------------------------------------------------------------
extern "C" void kernel_launch(void* const* d_in, const int* in_sizes, int n_in,
                              void* d_out, int out_size, void* d_ws, size_t ws_size,
                              hipStream_t stream) {
    const int* sid = (const int*)d_in[0];
    const int* eid = (const int*)d_in[1];
    // d_in[2] q_mask unused
    const float* stu_emb = (const float*)d_in[3];
    const float* exer_emb = (const float*)d_in[4];
    const float* know_emb = (const float*)d_in[5];
    const float* impact_emb = (const float*)d_in[6];
    const int* s_rows = (const int*)d_in[7];
    const int* s_cols = (const int*)d_in[8];
    const float* s_vals = (const float*)d_in[9];
    const int* e_rows = (const int*)d_in[10];
    const int* e_cols = (const int*)d_in[11];
    const float* e_vals = (const float*)d_in[12];
    const int* k_rows = (const int*)d_in[13];
    const int* k_cols = (const int*)d_in[14];
    const float* k_vals = (const float*)d_in[15];
    const float* W_stu = (const float*)d_in[16];
    const float* b_stu = (const float*)d_in[17];
    const float* W_exer = (const float*)d_in[18];
    const float* b_exer = (const float*)d_in[19];
    const float* W_know = (const float*)d_in[20];
    const float* b_know = (const float*)d_in[21];
    const float* W_disc = (const float*)d_in[22];
    const float* b_disc = (const float*)d_in[23];

    float* out = (float*)d_out;
    float* out_st = out;                       // [B,1000]
    float* out_df = out + 16384000;            // [B,1000]
    float* out_disc = out + 32768000;          // [B,1]
    float* out_kn = out + 32784384;            // [1000,128]
    float* out_imp = out + 32912384;           // [B,64]

    char* p = (char*)d_ws;
    auto alloc = [&](size_t bytes) -> char* {
        char* r = p;
        p += (bytes + 255) & ~(size_t)255;
        return r;
    };
    ushort* xb_s = (ushort*)alloc((size_t)S_N * 64 * 2);   // bf16 embeddings
    ushort* xb_e = (ushort*)alloc((size_t)E_N * 64 * 2);
    ushort* xb_k = (ushort*)alloc((size_t)K_N * 64 * 2);
    ushort* bufA_s = (ushort*)alloc((size_t)S_N * 64 * 2);
    ushort* bufB_s = (ushort*)alloc((size_t)S_N * 64 * 2);
    ushort* bufA_e = (ushort*)alloc((size_t)E_N * 64 * 2);
    ushort* bufB_e = (ushort*)alloc((size_t)E_N * 64 * 2);
    ushort* bufA_k = (ushort*)alloc((size_t)K_N * 64 * 2);
    ushort* bufB_k = (ushort*)alloc((size_t)K_N * 64 * 2);
    float* bacc_s = (float*)alloc((size_t)B_N * 64 * 4);
    float* bacc_e = (float*)alloc((size_t)B_N * 64 * 4);
    float* kacc = (float*)alloc((size_t)K_N * 64 * 4);
    __hip_bfloat16* st_b = (__hip_bfloat16*)alloc((size_t)B_N * 128 * 2);
    __hip_bfloat16* df_b = (__hip_bfloat16*)alloc((size_t)B_N * 128 * 2);
    __hip_bfloat16* kn_b = (__hip_bfloat16*)alloc((size_t)1024 * 128 * 2);
    // counters: cnt_s/cnt_e/cnt_k + bucket counters, contiguous for one memset
    int* cnt_s = (int*)alloc((size_t)(S_N + E_N + K_N + NB_TOT) * 4);
    int* cnt_e = cnt_s + S_N;
    int* cnt_k = cnt_e + E_N;
    int* bcnt = cnt_k + K_N;
    int* rp_s = (int*)alloc((size_t)(S_N + 1) * 4);
    int* rp_e = (int*)alloc((size_t)(E_N + 1) * 4);
    int* rp_k = (int*)alloc((size_t)(K_N + 1) * 4);
    int2* stg_s = (int2*)alloc((size_t)NNZ_S * 8);
    int2* stg_e = (int2*)alloc((size_t)NNZ_E * 8);
    int2* stg_k = (int2*)alloc((size_t)NNZ_K * 8);
    int2* pr_s = (int2*)alloc((size_t)NNZ_S * 8);
    int2* pr_e = (int2*)alloc((size_t)NNZ_E * 8);
    int2* pr_k = (int2*)alloc((size_t)NNZ_K * 8);
    int* partials = (int*)alloc(CH_TOT * 4);
    int* chunk_off = (int*)alloc(CH_TOT * 4);

    // ---- CSR build
    hipMemsetAsync(cnt_s, 0, (size_t)(S_N + E_N + K_N + NB_TOT) * 4, stream);
    count_kernel<<<NNZ_TOT / 256, 256, 0, stream>>>(s_rows, e_rows, k_rows, cnt_s, cnt_e, cnt_k);
    scan_a<<<CH_TOT, 256, 0, stream>>>(cnt_s, cnt_e, cnt_k, partials);
    scan_b<<<1, 64, 0, stream>>>(partials, chunk_off, rp_s, rp_e, rp_k);
    scan_c<<<CH_TOT, 256, 0, stream>>>(cnt_s, cnt_e, cnt_k, chunk_off, rp_s, rp_e, rp_k);
    stage1_bin<<<SB_TOT, 256, 0, stream>>>(
        s_rows, s_cols, s_vals, e_rows, e_cols, e_vals, k_rows, k_cols, k_vals,
        rp_s, rp_e, rp_k, bcnt, stg_s, stg_e, stg_k);
    stage2_place<<<NB_TOT, 256, 0, stream>>>(rp_s, stg_s, pr_s,
                                             rp_e, stg_e, pr_e,
                                             rp_k, stg_k, pr_k);

    // ---- bf16 convert of embeddings (spmm inputs)
    const int conv_blocks = ((S_N + E_N + K_N) * 64 / 4 + 255) / 256;
    convert_bf16<<<conv_blocks, 256, 0, stream>>>(stu_emb, exer_emb, know_emb, xb_s, xb_e, xb_k);

    // ---- convolution: G1(emb f32), L1, G2(cur1), L2, G3(cur2), L3
    const int gather_blocks = (2 * B_N * 64 + K_N * 64) / 256;
    const int spmm_blocks = (S_N + E_N + K_N + 3) / 4;
    gather_init<<<gather_blocks, 256, 0, stream>>>(sid, eid, stu_emb, exer_emb, know_emb,
                                                   bacc_s, bacc_e, kacc);
    spmm3<<<spmm_blocks, 256, 0, stream>>>(rp_s, pr_s, xb_s, bufA_s,
                                           rp_e, pr_e, xb_e, bufA_e,
                                           rp_k, pr_k, xb_k, bufA_k);
    gather_accb<<<gather_blocks, 256, 0, stream>>>(sid, eid, bufA_s, bufA_e, bufA_k,
                                                   bacc_s, bacc_e, kacc);
    spmm3<<<spmm_blocks, 256, 0, stream>>>(rp_s, pr_s, bufA_s, bufB_s,
                                           rp_e, pr_e, bufA_e, bufB_e,
                                           rp_k, pr_k, bufA_k, bufB_k);
    gather_accb<<<gather_blocks, 256, 0, stream>>>(sid, eid, bufB_s, bufB_e, bufB_k,
                                                   bacc_s, bacc_e, kacc);
    spmm3<<<spmm_blocks, 256, 0, stream>>>(rp_s, pr_s, bufB_s, bufA_s,
                                           rp_e, pr_e, bufB_e, bufA_e,
                                           rp_k, pr_k, bufB_k, bufA_k);
    // cur3 now in bufA_* (bf16); dense stage folds the last gather and the /4 scale

    // ---- dense stage
    dense_mm<<<dim3(B_N / 2, 2), 256, 0, stream>>>(sid, eid, bacc_s, bufA_s, bacc_e, bufA_e,
                                                   W_stu, b_stu, W_exer, b_exer, st_b, df_b);
    know_mm<<<512, 256, 0, stream>>>(kacc, bufA_k, W_know, b_know, out_kn, kn_b);
    disc_kernel<<<B_N / 4, 256, 0, stream>>>(eid, bacc_e, bufA_e, W_disc, b_disc, out_disc);
    impact_kernel<<<B_N * 64 / 256, 256, 0, stream>>>(eid, impact_emb, out_imp);

    // ---- big GEMMs: [B,128] @ kn^T -> [B,1000], both in one kernel (z = 0/1)
    big_mm<<<dim3(16, B_N / 64, 2), 256, 0, stream>>>(st_b, df_b, kn_b, out_st, out_df);
}